// Round 16
// baseline (326.741 us; speedup 1.0000x reference)
//
#include <hip/hip_runtime.h>

typedef __attribute__((ext_vector_type(4))) float f32x4;
typedef __attribute__((ext_vector_type(8))) _Float16 f16x8;
typedef __attribute__((ext_vector_type(4))) unsigned short u16x4;

#define NB 8
#define LLEN 512
#define DD 768
#define MW 12
#define HH 384
#define TT (NB * LLEN)      // 4096 tokens
#define SS (LLEN * MW)      // 6144 spans per batch
#define RB 576              // X/R rows per batch (513 used; 9 integer 64-panels)
#define MX (NB * RB)        // 4608 rows

#define TILESB 108          // GEMM tiles per batch (9 panels x 12 n-cols)
#define NTILES (NB * TILESB)// 864
#define NPROD 256           // producer blocks
#define NBLK 768            // total blocks (3/CU -> all co-resident)
#define RPB 64              // out-rows per writer share (49152/768)

#define PREPX_BLOCKS ((MX * 192) / 256)   // 3456
#define PREPW_BLOCKS ((DD * 192) / 256)   // 576
#define PREP_BLOCKS (PREPX_BLOCKS + PREPW_BLOCKS)

// ---------- helpers ----------
__device__ __forceinline__ unsigned short f2h(float x) {
  _Float16 h = (_Float16)x;               // RNE
  return __builtin_bit_cast(unsigned short, h);
}
__device__ __forceinline__ void gload_lds16(const void* g, void* l) {
  __builtin_amdgcn_global_load_lds(
      (const __attribute__((address_space(1))) unsigned int*)g,
      (__attribute__((address_space(3))) unsigned int*)l, 16, 0, 0);
}

// ---------- prep ----------
// X[b*RB + t + 1][0:384]   = fwd[b][t]   (ss at t==-1; clamped past end, unused)
// X[b*RB + t + 1][384:768] = bwd[b][t+1] (es at t>=511)
// Wp[e][k] = fp16(W[e][k]); also zeroes the per-batch tile counters.
__global__ __launch_bounds__(256) void prep_k(const float* __restrict__ h,
                                              const float* __restrict__ W,
                                              const float* __restrict__ ss,
                                              const float* __restrict__ es,
                                              unsigned short* __restrict__ X,
                                              unsigned short* __restrict__ Wp,
                                              int* __restrict__ flags) {
  int bid = blockIdx.x;
  if (bid < PREPX_BLOCKS) {
    int idx = bid * 256 + threadIdx.x;        // over MX*192 u16x4 chunks
    int r = idx / 192;
    int c = (idx - r * 192) * 4;
    int b = r / RB;
    int t = r - b * RB - 1;                   // -1..574
    const float* src;
    if (c < HH) {
      src = (t == -1) ? (ss + c) : (h + ((size_t)b * LLEN + min(t, LLEN - 1)) * DD + c);
    } else {
      src = (t >= LLEN - 1) ? (es + (c - HH))
                            : (h + ((size_t)b * LLEN + (t + 1)) * DD + c);
    }
    f32x4 f = *(const f32x4*)src;
    u16x4 v;
#pragma unroll
    for (int j = 0; j < 4; ++j) v[j] = f2h(f[j]);
    *(u16x4*)(X + (size_t)r * DD + c) = v;
  } else {
    if (bid == PREPX_BLOCKS && threadIdx.x == 0) {
#pragma unroll
      for (int i = 0; i < NB; ++i) flags[i * 16] = 0;   // zero tile counters
    }
    int idx = (bid - PREPX_BLOCKS) * 256 + threadIdx.x;  // over DD*192 chunks
    int e = idx / 192;
    int c = (idx - e * 192) * 4;
    f32x4 f = *(const f32x4*)(W + (size_t)e * DD + c);
    u16x4 v;
#pragma unroll
    for (int j = 0; j < 4; ++j) v[j] = f2h(f[j]);
    *(u16x4*)(Wp + (size_t)e * DD + c) = v;
  }
}

// ---------- mega: producer/consumer wave-specialized ----------
// Blocks 0..255: produce 864 R-tiles (BM=64,BN=64,K=768) batch-major, ~3.4
//   rounds; per completed tile: threadfence + release-atomic on flags[batch].
//   Then become writers for the LAST third of out rows.
// Blocks 256..767: writers for the FIRST two thirds; spin (acquire, s_sleep)
//   until their batch's 108 tiles are done, then stream 64 out rows each.
// Batches 0-1 ready after round 1 (~3us) -> writes overlap remaining GEMM.
__global__ __launch_bounds__(256) void mega_k(const unsigned short* __restrict__ X,
                                              const unsigned short* __restrict__ Wp,
                                              const int* __restrict__ span,
                                              const float* __restrict__ bias,
                                              unsigned short* __restrict__ R,
                                              int* __restrict__ flags,
                                              float* __restrict__ out) {
  __shared__ char stg[16384];              // As [64][128B] + Bs [64][128B]
  const int bid = blockIdx.x;
  const int tid = threadIdx.x;

  if (bid < NPROD) {
    char* As = stg;
    char* Bs = stg + 8192;
    const char* Xb = (const char*)X;
    const char* Wb = (const char*)Wp;
    const int lane = tid & 63;
    const int wv = tid >> 6;
    const int wr = wv >> 1, wc2 = wv & 1;  // 2x2 waves -> 32x32 each
    const int l16 = lane & 15, l4 = lane >> 4;

    for (int t = bid; t < NTILES; t += NPROD) {
      const int b = t / TILESB;
      const int rr0 = t - b * TILESB;
      const int mp = rr0 / 12, nc = rr0 - mp * 12;
      const size_t r0 = (size_t)b * RB + mp * 64;
      const int c0 = nc * 64;

      f32x4 acc[2][2] = {};
      for (int kc = 0; kc < DD; kc += 64) {
#pragma unroll
        for (int r2 = 0; r2 < 2; ++r2) {
          int o = (r2 * 256 + tid) * 16;
          int rr = o >> 7, cb = o & 127;
          gload_lds16(Xb + ((r0 + rr) * DD + kc) * 2 + cb, As + o);
          gload_lds16(Wb + ((size_t)(c0 + rr) * DD + kc) * 2 + cb, Bs + o);
        }
        __syncthreads();
        f16x8 af[2][2], bf[2][2];
#pragma unroll
        for (int ks = 0; ks < 2; ++ks) {
#pragma unroll
          for (int m = 0; m < 2; ++m) {
            af[ks][m] = *(const f16x8*)(As + (wr * 32 + m * 16 + l16) * 128 + ks * 64 + l4 * 16);
            bf[ks][m] = *(const f16x8*)(Bs + (wc2 * 32 + m * 16 + l16) * 128 + ks * 64 + l4 * 16);
          }
        }
#pragma unroll
        for (int m = 0; m < 2; ++m)
#pragma unroll
          for (int n = 0; n < 2; ++n) {
            acc[m][n] = __builtin_amdgcn_mfma_f32_16x16x32_f16(af[0][m], bf[0][n], acc[m][n], 0, 0, 0);
            acc[m][n] = __builtin_amdgcn_mfma_f32_16x16x32_f16(af[1][m], bf[1][n], acc[m][n], 0, 0, 0);
          }
        __syncthreads();
      }
      // epilogue: D row=(lane>>4)*4+reg, col=lane&15; store R fp16
#pragma unroll
      for (int m = 0; m < 2; ++m) {
        size_t grow = r0 + wr * 32 + m * 16 + l4 * 4;
#pragma unroll
        for (int n = 0; n < 2; ++n) {
          int gcol = c0 + wc2 * 32 + n * 16 + l16;
#pragma unroll
          for (int r = 0; r < 4; ++r)
            R[(grow + r) * DD + gcol] = f2h(acc[m][n][r]);
        }
      }
      __threadfence();                     // all this thread's R stores device-visible
      __syncthreads();                     // whole block's stores fenced
      if (tid == 0)
        __hip_atomic_fetch_add(&flags[b * 16], 1, __ATOMIC_RELEASE, __HIP_MEMORY_SCOPE_AGENT);
    }
  }

  // ---- writer role (all blocks) ----
  const int wblk = (bid < NPROD) ? (512 + bid) : (bid - NPROD);
  const int row0 = wblk * RPB;             // 64 rows, single batch (6144 = 96*64)
  const int b = row0 / SS;
  if (tid == 0) {
    while (__hip_atomic_load(&flags[b * 16], __ATOMIC_ACQUIRE, __HIP_MEMORY_SCOPE_AGENT) < TILESB)
      __builtin_amdgcn_s_sleep(8);
  }
  __syncthreads();

  const size_t rbase = (size_t)b * RB;
  const u16x4* R4 = (const u16x4*)R;
  const int2* sp2 = (const int2*)span;
  f32x4* out4 = (f32x4*)out;
#pragma unroll 4
  for (int it = 0; it < (RPB * 192) / 256; ++it) {   // 48 iters
    int c = it * 256 + tid;
    int rl = c / 192;
    int e4 = c - rl * 192;
    int grow = row0 + rl;
    int2 se = sp2[grow];
    u16x4 pe = R4[(rbase + se.y + 1) * 192 + e4];    // R[end]
    u16x4 mq = R4[(rbase + se.x) * 192 + e4];        // R[start-1]
    f32x4 bb = ((const f32x4*)bias)[e4];
    f32x4 rr;
#pragma unroll
    for (int j = 0; j < 4; ++j) {
      float hi = __builtin_bit_cast(float, (unsigned)((unsigned short*)&pe)[j] << 16);
      (void)hi;
      float xe = (float)__builtin_bit_cast(_Float16, ((unsigned short*)&pe)[j]);
      float xs = (float)__builtin_bit_cast(_Float16, ((unsigned short*)&mq)[j]);
      rr[j] = fmaxf(xe - xs + bb[j], 0.f);
    }
    out4[(size_t)grow * 192 + e4] = rr;
  }
}

// ---------- naive fallback (only if ws too small) ----------
__global__ __launch_bounds__(256) void naive_k(const float* __restrict__ h,
                                               const int* __restrict__ span,
                                               const float* __restrict__ W,
                                               const float* __restrict__ bias,
                                               const float* __restrict__ ss,
                                               const float* __restrict__ es,
                                               float* __restrict__ out) {
  int bs = blockIdx.x;
  int b = bs / SS;
  int start = span[(size_t)bs * 2 + 0];
  int end   = span[(size_t)bs * 2 + 1];
  __shared__ float rep[DD];
  const float* hb = h + (size_t)b * LLEN * DD;
  for (int k = threadIdx.x; k < HH; k += blockDim.x) {
    float fs = (start == 0) ? ss[k] : hb[(size_t)(start - 1) * DD + k];
    rep[k] = hb[(size_t)end * DD + k] - fs;
    float bstart = (end + 1 >= LLEN) ? es[k] : hb[(size_t)(end + 1) * DD + HH + k];
    rep[HH + k] = bstart - hb[(size_t)start * DD + HH + k];
  }
  __syncthreads();
  for (int e = threadIdx.x; e < DD; e += blockDim.x) {
    const float* w = W + (size_t)e * DD;
    float acc = bias[e];
    for (int k = 0; k < DD; k += 4) {
      acc += rep[k] * w[k] + rep[k + 1] * w[k + 1] + rep[k + 2] * w[k + 2] + rep[k + 3] * w[k + 3];
    }
    out[(size_t)bs * DD + e] = fmaxf(acc, 0.f);
  }
}

extern "C" void kernel_launch(void* const* d_in, const int* in_sizes, int n_in,
                              void* d_out, int out_size, void* d_ws, size_t ws_size,
                              hipStream_t stream) {
  const float* h  = (const float*)d_in[0];
  const int* span = (const int*)d_in[1];
  const float* W  = (const float*)d_in[2];
  const float* bias = (const float*)d_in[3];
  const float* ss = (const float*)d_in[4];
  const float* es = (const float*)d_in[5];
  float* out = (float*)d_out;

  const size_t szX = (size_t)MX * DD * sizeof(unsigned short);    // 7.08 MB
  const size_t szW = (size_t)DD * DD * sizeof(unsigned short);    // 1.18 MB
  const size_t szR = (size_t)MX * DD * sizeof(unsigned short);    // 7.08 MB
  const size_t szF = 256 * sizeof(int);
  const size_t need = szX + szW + szR + szF;                      // ~15.3 MB

  if (ws_size < need) {
    naive_k<<<NB * SS, 256, 0, stream>>>(h, span, W, bias, ss, es, out);
    return;
  }

  char* ws = (char*)d_ws;
  unsigned short* X  = (unsigned short*)ws;                // [MX][DD] fp16
  unsigned short* Wp = X + (size_t)MX * DD;                // [DD][DD] fp16
  unsigned short* R  = Wp + (size_t)DD * DD;               // [MX][DD] fp16
  int* flags = (int*)(ws + szX + szW + szR);

  prep_k<<<PREP_BLOCKS, 256, 0, stream>>>(h, W, ss, es, X, Wp, flags);
  mega_k<<<NBLK, 256, 0, stream>>>(X, Wp, span, bias, R, flags, out);
}

// Round 20
// 75.093 us; speedup vs baseline: 4.3512x; 4.3512x over previous
//
#include <hip/hip_runtime.h>

typedef __attribute__((ext_vector_type(4))) float f32x4;
typedef __attribute__((ext_vector_type(8))) _Float16 f16x8;
typedef __attribute__((ext_vector_type(4))) unsigned short u16x4;

#define NB 8
#define LLEN 512
#define DD 768
#define MW 12
#define HH 384
#define TT (NB * LLEN)      // 4096 tokens
#define SS (LLEN * MW)      // 6144 spans per batch
#define RB 528              // X rows per batch (513 used: t=-1..511, rest pad)
#define MX (NB * RB)        // 4224 X rows

#define BT 32               // tokens per fused block
#define BE 128              // e-slice per block (4 waves x 32 cols)
#define PRT 36              // Rt pitch in f32 (144 B: 16B-aligned rows)

#define PREPX_BLOCKS ((MX * 192) / 256)   // 3168
#define PREPW_BLOCKS ((DD * 192) / 256)   // 576
#define PREP_BLOCKS (PREPX_BLOCKS + PREPW_BLOCKS)

// ---------- helpers ----------
__device__ __forceinline__ unsigned short f2h(float x) {
  _Float16 h = (_Float16)x;               // RNE
  return __builtin_bit_cast(unsigned short, h);
}

// ---------- prep ----------
// X[b*RB + t + 1][0:384]   = fwd[b][t]   (ss at t==-1, clamped past 511)
// X[b*RB + t + 1][384:768] = bwd[b][t+1] (es at t>=511)
// Wp[e][k] = fp16(W[e][k])
__global__ __launch_bounds__(256) void prep_k(const float* __restrict__ h,
                                              const float* __restrict__ W,
                                              const float* __restrict__ ss,
                                              const float* __restrict__ es,
                                              unsigned short* __restrict__ X,
                                              unsigned short* __restrict__ Wp) {
  int bid = blockIdx.x;
  if (bid < PREPX_BLOCKS) {
    int idx = bid * 256 + threadIdx.x;        // over MX*192 u16x4 chunks
    int r = idx / 192;
    int c = (idx - r * 192) * 4;
    int b = r / RB;
    int t = r - b * RB - 1;                   // -1..526
    const float* src;
    if (c < HH) {
      src = (t == -1) ? (ss + c) : (h + ((size_t)b * LLEN + min(t, LLEN - 1)) * DD + c);
    } else {
      src = (t >= LLEN - 1) ? (es + (c - HH))
                            : (h + ((size_t)b * LLEN + (t + 1)) * DD + c);
    }
    f32x4 f = *(const f32x4*)src;
    u16x4 v;
#pragma unroll
    for (int j = 0; j < 4; ++j) v[j] = f2h(f[j]);
    *(u16x4*)(X + (size_t)r * DD + c) = v;
  } else {
    int idx = (bid - PREPX_BLOCKS) * 256 + threadIdx.x;  // over DD*192 chunks
    int e = idx / 192;
    int c = (idx - e * 192) * 4;
    f32x4 f = *(const f32x4*)(W + (size_t)e * DD + c);
    u16x4 v;
#pragma unroll
    for (int j = 0; j < 4; ++j) v[j] = f2h(f[j]);
    *(u16x4*)(Wp + (size_t)e * DD + c) = v;
  }
}

// ---------- fused telescoped GEMM + assemble, barrier-free K-loop ----------
// Per block: batch b, tokens [T0,T0+32), e-slice [E0,E0+128); wave wv owns
// cols [E0+wv*32, +32) END-TO-END: MFMA fragments loaded DIRECTLY from
// global (X, Wp are L2-resident -- LDS staging is pure overhead, no barriers,
// no vmcnt drains; compiler counts waitcnt, 12 waves/CU hide latency), acc ->
// private Rt LDS slice (same-wave ds order is automatic), assemble its own
// 32 cols. ONE __syncthreads total (spans). Grid 768 = 3/CU; bid%8 = g%8 ->
// a window's 6 e-siblings share an XCD (X rows fetched into L2 once).
__global__ __launch_bounds__(256, 3) void fused_k(const unsigned short* __restrict__ X,
                                                  const unsigned short* __restrict__ Wp,
                                                  const int* __restrict__ span,
                                                  const float* __restrict__ bias,
                                                  float* __restrict__ out) {
  __shared__ float Rt[4][48 * PRT];        // per-wave 32-col R slices, 27648 B
  __shared__ int2 spans[BT * MW];          // 3072 B

  const int bid = blockIdx.x;
  const int g = ((bid >> 3) / 6) * 8 + (bid & 7);   // window id 0..127
  const int ec = (bid >> 3) % 6;
  const int b = g >> 4;
  const int T0 = (g & 15) * BT;
  const int E0 = ec * BE;

  const int tid = threadIdx.x;
  const int lane = tid & 63;
  const int wv = tid >> 6;
  const int l16 = lane & 15, l4 = lane >> 4;

  {
    const int2* sp = (const int2*)span + (size_t)b * SS + (size_t)T0 * MW;
    for (int s = tid; s < BT * MW; s += 256) spans[s] = sp[s];
  }
  __syncthreads();                         // the only block-wide barrier

  // ---- GEMM: M=48 window rows x 32 own cols, K=768, operands from global ----
  const unsigned short* Xw = X + ((size_t)b * RB + T0) * DD;        // row0 = t(T0-1)
  const unsigned short* Wn = Wp + (size_t)(E0 + wv * 32) * DD;

  f32x4 acc[3][2] = {};
#pragma unroll 4
  for (int ki = 0; ki < 12; ++ki) {
    const int kc = ki * 64;
    f16x8 af[2][3], bf[2][2];
#pragma unroll
    for (int ks = 0; ks < 2; ++ks) {
#pragma unroll
      for (int m = 0; m < 3; ++m)
        af[ks][m] = *(const f16x8*)&Xw[(size_t)(m * 16 + l16) * DD + kc + ks * 32 + l4 * 8];
#pragma unroll
      for (int n = 0; n < 2; ++n)
        bf[ks][n] = *(const f16x8*)&Wn[(size_t)(n * 16 + l16) * DD + kc + ks * 32 + l4 * 8];
    }
#pragma unroll
    for (int m = 0; m < 3; ++m)
#pragma unroll
      for (int n = 0; n < 2; ++n) {
        acc[m][n] = __builtin_amdgcn_mfma_f32_16x16x32_f16(af[0][m], bf[0][n], acc[m][n], 0, 0, 0);
        acc[m][n] = __builtin_amdgcn_mfma_f32_16x16x32_f16(af[1][m], bf[1][n], acc[m][n], 0, 0, 0);
      }
  }

  // ---- acc -> private Rt slice (f32; D row=(lane>>4)*4+reg, col=lane&15) ----
  float* Rw = Rt[wv];
#pragma unroll
  for (int m = 0; m < 3; ++m)
#pragma unroll
    for (int n = 0; n < 2; ++n)
#pragma unroll
      for (int r = 0; r < 4; ++r)
        Rw[(m * 16 + l4 * 4 + r) * PRT + n * 16 + l16] = acc[m][n][r];
  // same-wave ds_write -> ds_read ordering is hardware-automatic (lgkmcnt)

  // ---- assemble own 32 cols: out = relu(R[end] - R[start-1] + bias) ----
  const int e4 = lane & 7;                 // 8 f32x4 chunks of 32 cols
  const int lr = lane >> 3;                // 8 rows per iter
  const f32x4 bb = ((const f32x4*)bias)[(E0 + wv * 32) / 4 + e4];
  f32x4* outB = (f32x4*)out + ((size_t)b * SS + (size_t)T0 * MW) * (DD / 4)
              + (E0 + wv * 32) / 4 + e4;

#pragma unroll 4
  for (int it = 0; it < 48; ++it) {
    const int lw = it * 8 + lr;            // token-width row 0..383
    const int2 se = spans[lw];
    f32x4 pe = *(const f32x4*)&Rw[(se.y - T0 + 1) * PRT + e4 * 4];   // R[end]
    f32x4 mq = *(const f32x4*)&Rw[(se.x - T0) * PRT + e4 * 4];       // R[start-1]
    f32x4 rr;
#pragma unroll
    for (int j = 0; j < 4; ++j) rr[j] = fmaxf(pe[j] - mq[j] + bb[j], 0.f);
    outB[(size_t)lw * (DD / 4)] = rr;
  }
}

// ---------- naive fallback (only if ws too small) ----------
__global__ __launch_bounds__(256) void naive_k(const float* __restrict__ h,
                                               const int* __restrict__ span,
                                               const float* __restrict__ W,
                                               const float* __restrict__ bias,
                                               const float* __restrict__ ss,
                                               const float* __restrict__ es,
                                               float* __restrict__ out) {
  int bs = blockIdx.x;
  int b = bs / SS;
  int start = span[(size_t)bs * 2 + 0];
  int end   = span[(size_t)bs * 2 + 1];
  __shared__ float rep[DD];
  const float* hb = h + (size_t)b * LLEN * DD;
  for (int k = threadIdx.x; k < HH; k += blockDim.x) {
    float fs = (start == 0) ? ss[k] : hb[(size_t)(start - 1) * DD + k];
    rep[k] = hb[(size_t)end * DD + k] - fs;
    float bstart = (end + 1 >= LLEN) ? es[k] : hb[(size_t)(end + 1) * DD + HH + k];
    rep[HH + k] = bstart - hb[(size_t)start * DD + HH + k];
  }
  __syncthreads();
  for (int e = threadIdx.x; e < DD; e += blockDim.x) {
    const float* w = W + (size_t)e * DD;
    float acc = bias[e];
    for (int k = 0; k < DD; k += 4) {
      acc += rep[k] * w[k] + rep[k + 1] * w[k + 1] + rep[k + 2] * w[k + 2] + rep[k + 3] * w[k + 3];
    }
    out[(size_t)bs * DD + e] = fmaxf(acc, 0.f);
  }
}

extern "C" void kernel_launch(void* const* d_in, const int* in_sizes, int n_in,
                              void* d_out, int out_size, void* d_ws, size_t ws_size,
                              hipStream_t stream) {
  const float* h  = (const float*)d_in[0];
  const int* span = (const int*)d_in[1];
  const float* W  = (const float*)d_in[2];
  const float* bias = (const float*)d_in[3];
  const float* ss = (const float*)d_in[4];
  const float* es = (const float*)d_in[5];
  float* out = (float*)d_out;

  const size_t szX = (size_t)MX * DD * sizeof(unsigned short);    // 6.49 MB
  const size_t szW = (size_t)DD * DD * sizeof(unsigned short);    // 1.18 MB
  const size_t need = szX + szW;                                  // ~7.7 MB

  if (ws_size < need) {
    naive_k<<<NB * SS, 256, 0, stream>>>(h, span, W, bias, ss, es, out);
    return;
  }

  char* ws = (char*)d_ws;
  unsigned short* X  = (unsigned short*)ws;                // [MX][DD] fp16
  unsigned short* Wp = X + (size_t)MX * DD;                // [DD][DD] fp16

  prep_k<<<PREP_BLOCKS, 256, 0, stream>>>(h, W, ss, es, X, Wp);
  fused_k<<<768, 256, 0, stream>>>(X, Wp, span, bias, out);
}

// Round 21
// 55.150 us; speedup vs baseline: 5.9246x; 1.3616x over previous
//
#include <hip/hip_runtime.h>

typedef __attribute__((ext_vector_type(4))) float f32x4;
typedef __attribute__((ext_vector_type(8))) _Float16 f16x8;
typedef __attribute__((ext_vector_type(4))) unsigned short u16x4;

#define NB 8
#define LLEN 512
#define DD 768
#define MW 12
#define HH 384
#define TT (NB * LLEN)      // 4096 tokens
#define SS (LLEN * MW)      // 6144 spans per batch
#define RB 528              // X rows per batch (513 used: t=-1..511, rest pad)
#define MX (NB * RB)        // 4224 X rows

#define BT 32               // tokens per fused block
#define BE 128              // e-slice per fused block
#define WR 48               // R-window rows (44 used: t in [T0-1, T0+42])
#define PR 136              // R-tile LDS pitch in fp16

#define PREPX_BLOCKS ((MX * 192) / 256)   // 3168
#define PREPW_BLOCKS ((DD * 192) / 256)   // 576
#define PREP_BLOCKS (PREPX_BLOCKS + PREPW_BLOCKS)

// ---------- helpers ----------
__device__ __forceinline__ unsigned short f2h(float x) {
  _Float16 h = (_Float16)x;               // RNE
  return __builtin_bit_cast(unsigned short, h);
}
__device__ __forceinline__ float h2f(unsigned short u) {
  return (float)__builtin_bit_cast(_Float16, u);
}
__device__ __forceinline__ void gload_lds16(const void* g, void* l) {
  __builtin_amdgcn_global_load_lds(
      (const __attribute__((address_space(1))) unsigned int*)g,
      (__attribute__((address_space(3))) unsigned int*)l, 16, 0, 0);
}

// ---------- prep ----------
// X[b*RB + t + 1][0:384]   = fwd[b][t]   (ss at t==-1, clamped past 511)
// X[b*RB + t + 1][384:768] = bwd[b][t+1] (es at t>=511)
// Wp[e][k] = fp16(W[e][k])
__global__ __launch_bounds__(256) void prep_k(const float* __restrict__ h,
                                              const float* __restrict__ W,
                                              const float* __restrict__ ss,
                                              const float* __restrict__ es,
                                              unsigned short* __restrict__ X,
                                              unsigned short* __restrict__ Wp) {
  int bid = blockIdx.x;
  if (bid < PREPX_BLOCKS) {
    int idx = bid * 256 + threadIdx.x;        // over MX*192 u16x4 chunks
    int r = idx / 192;
    int c = (idx - r * 192) * 4;
    int b = r / RB;
    int t = r - b * RB - 1;                   // -1..526
    const float* src;
    if (c < HH) {
      src = (t == -1) ? (ss + c) : (h + ((size_t)b * LLEN + min(t, LLEN - 1)) * DD + c);
    } else {
      src = (t >= LLEN - 1) ? (es + (c - HH))
                            : (h + ((size_t)b * LLEN + (t + 1)) * DD + c);
    }
    f32x4 f = *(const f32x4*)src;
    u16x4 v;
#pragma unroll
    for (int j = 0; j < 4; ++j) v[j] = f2h(f[j]);
    *(u16x4*)(X + (size_t)r * DD + c) = v;
  } else {
    int idx = (bid - PREPX_BLOCKS) * 256 + threadIdx.x;  // over DD*192 chunks
    int e = idx / 192;
    int c = (idx - e * 192) * 4;
    f32x4 f = *(const f32x4*)(W + (size_t)e * DD + c);
    u16x4 v;
#pragma unroll
    for (int j = 0; j < 4; ++j) v[j] = f2h(f[j]);
    *(u16x4*)(Wp + (size_t)e * DD + c) = v;
  }
}

// ---------- fused telescoped GEMM + assemble (R13 structure, BK=128) ----------
// Per block: batch b, tokens [T0, T0+31], e-slice [E0, E0+128).
// Phase 1: R-window GEMM, M=48, N=128, K=768 in SIX BK=128 steps (12 barrier
//          drains instead of 24 -- the measured serial cost of the K-loop).
// Phase 2: acc -> fp16 R tile in LDS (union over dead staging).
// Phase 3: out[l,w] = relu(R[end] - R[start-1] + bias), 2 LDS gathers/row.
// LDS 47 KB -> still 3 blocks/CU co-resident. bid%8 = g%8: a window's 6
// e-siblings share an XCD (X rows L2-hot).
__global__ __launch_bounds__(256) void fused_k(const unsigned short* __restrict__ X,
                                               const unsigned short* __restrict__ Wp,
                                               const int* __restrict__ span,
                                               const float* __restrict__ bias,
                                               float* __restrict__ out) {
  __shared__ char lds[WR * 256 + BE * 256];   // 45056 B staging / R-tile union
  __shared__ int2 spans[BT * MW];             // 3072 B

  const int bid = blockIdx.x;
  const int g = ((bid >> 3) / 6) * 8 + (bid & 7);   // window id 0..127
  const int ec = (bid >> 3) % 6;
  const int b = g >> 4;
  const int T0 = (g & 15) * BT;
  const int E0 = ec * BE;

  const int tid = threadIdx.x;
  const int lane = tid & 63;
  const int wc = tid >> 6;                 // wave -> 32-col slice of N=128
  const int l16 = lane & 15, l4 = lane >> 4;

  // stage this block's 384 spans
  {
    const int2* sp = (const int2*)span + (size_t)b * SS + (size_t)T0 * MW;
    for (int s = tid; s < BT * MW; s += 256) spans[s] = sp[s];
  }

  char* As = lds;                          // [48][256B]   X window slice
  char* Bs = lds + WR * 256;               // [128][256B]  Wp slice

  const size_t xbase = (size_t)b * RB + T0;   // X row of window row 0 (t=T0-1)
  const char* Xb = (const char*)X;
  const char* Wb = (const char*)Wp;

  f32x4 acc[3][2] = {};

#pragma unroll
  for (int ki = 0; ki < 6; ++ki) {
    const int kc = ki * 128;
    // A: 48 rows x 256 B = 12288 B (3 rounds of 256x16B)
#pragma unroll
    for (int r = 0; r < 3; ++r) {
      int o = (r * 256 + tid) * 16;
      int rr = o >> 8, cb = o & 255;
      gload_lds16(Xb + ((xbase + rr) * DD + kc) * 2 + cb, As + o);
    }
    // B: 128 rows x 256 B = 32768 B (8 rounds)
#pragma unroll
    for (int r = 0; r < 8; ++r) {
      int o = (r * 256 + tid) * 16;
      int rr = o >> 8, cb = o & 255;
      gload_lds16(Wb + ((size_t)(E0 + rr) * DD + kc) * 2 + cb, Bs + o);
    }
    __syncthreads();

#pragma unroll
    for (int ks = 0; ks < 4; ++ks) {       // 4 x K=32 sub-steps
      f16x8 af[3], bf[2];
#pragma unroll
      for (int m = 0; m < 3; ++m)
        af[m] = *(const f16x8*)(As + (m * 16 + l16) * 256 + ks * 64 + l4 * 16);
#pragma unroll
      for (int n = 0; n < 2; ++n)
        bf[n] = *(const f16x8*)(Bs + (wc * 32 + n * 16 + l16) * 256 + ks * 64 + l4 * 16);
#pragma unroll
      for (int m = 0; m < 3; ++m)
#pragma unroll
        for (int n = 0; n < 2; ++n)
          acc[m][n] = __builtin_amdgcn_mfma_f32_16x16x32_f16(af[m], bf[n], acc[m][n], 0, 0, 0);
    }
    __syncthreads();                       // staging reusable / dead after last iter
  }

  // Phase 2: acc -> fp16 R tile (unions over dead staging)
  unsigned short* Rt = (unsigned short*)lds;   // [48][PR]; row rr = R[T0-1+rr]
#pragma unroll
  for (int m = 0; m < 3; ++m) {
    int row = m * 16 + l4 * 4;
#pragma unroll
    for (int n = 0; n < 2; ++n) {
      int col = wc * 32 + n * 16 + l16;
#pragma unroll
      for (int r = 0; r < 4; ++r)
        Rt[(row + r) * PR + col] = f2h(acc[m][n][r]);
    }
  }
  __syncthreads();

  // Phase 3: out[b, (T0+l)*12+w, E0:E0+128] = relu(R[end] - R[start-1] + b)
  const u16x4* R4 = (const u16x4*)Rt;      // row pitch PR/4 = 34
  const f32x4* bias4 = (const f32x4*)bias + (E0 >> 2);
  f32x4* out4 = (f32x4*)out + ((size_t)b * SS + (size_t)T0 * MW) * (DD / 4) + (E0 >> 2);

  const int e4 = tid & 31;                 // 32 u16x4 chunks per 128-e slice
  int lw = tid >> 5;                       // token-width row, +8 per iter
  const f32x4 bb = bias4[e4];
#pragma unroll 4
  for (int it = 0; it < (BT * MW) / 8; ++it) {   // 48 iters
    const int2 se = spans[lw];
    u16x4 pe = R4[(se.y - T0 + 1) * 34 + e4];    // R[end]
    u16x4 mq = R4[(se.x - T0) * 34 + e4];        // R[start-1]
    f32x4 r;
#pragma unroll
    for (int j = 0; j < 4; ++j) {
      float x = h2f(pe[j]) - h2f(mq[j]) + bb[j];
      r[j] = fmaxf(x, 0.f);
    }
    out4[(size_t)lw * (DD / 4) + e4] = r;
    lw += 8;
  }
}

// ---------- naive fallback (only if ws too small) ----------
__global__ __launch_bounds__(256) void naive_k(const float* __restrict__ h,
                                               const int* __restrict__ span,
                                               const float* __restrict__ W,
                                               const float* __restrict__ bias,
                                               const float* __restrict__ ss,
                                               const float* __restrict__ es,
                                               float* __restrict__ out) {
  int bs = blockIdx.x;
  int b = bs / SS;
  int start = span[(size_t)bs * 2 + 0];
  int end   = span[(size_t)bs * 2 + 1];
  __shared__ float rep[DD];
  const float* hb = h + (size_t)b * LLEN * DD;
  for (int k = threadIdx.x; k < HH; k += blockDim.x) {
    float fs = (start == 0) ? ss[k] : hb[(size_t)(start - 1) * DD + k];
    rep[k] = hb[(size_t)end * DD + k] - fs;
    float bstart = (end + 1 >= LLEN) ? es[k] : hb[(size_t)(end + 1) * DD + HH + k];
    rep[HH + k] = bstart - hb[(size_t)start * DD + HH + k];
  }
  __syncthreads();
  for (int e = threadIdx.x; e < DD; e += blockDim.x) {
    const float* w = W + (size_t)e * DD;
    float acc = bias[e];
    for (int k = 0; k < DD; k += 4) {
      acc += rep[k] * w[k] + rep[k + 1] * w[k + 1] + rep[k + 2] * w[k + 2] + rep[k + 3] * w[k + 3];
    }
    out[(size_t)bs * DD + e] = fmaxf(acc, 0.f);
  }
}

extern "C" void kernel_launch(void* const* d_in, const int* in_sizes, int n_in,
                              void* d_out, int out_size, void* d_ws, size_t ws_size,
                              hipStream_t stream) {
  const float* h  = (const float*)d_in[0];
  const int* span = (const int*)d_in[1];
  const float* W  = (const float*)d_in[2];
  const float* bias = (const float*)d_in[3];
  const float* ss = (const float*)d_in[4];
  const float* es = (const float*)d_in[5];
  float* out = (float*)d_out;

  const size_t szX = (size_t)MX * DD * sizeof(unsigned short);    // 6.49 MB
  const size_t szW = (size_t)DD * DD * sizeof(unsigned short);    // 1.18 MB
  const size_t need = szX + szW;                                  // ~7.7 MB

  if (ws_size < need) {
    naive_k<<<NB * SS, 256, 0, stream>>>(h, span, W, bias, ss, es, out);
    return;
  }

  char* ws = (char*)d_ws;
  unsigned short* X  = (unsigned short*)ws;                // [MX][DD] fp16
  unsigned short* Wp = X + (size_t)MX * DD;                // [DD][DD] fp16

  prep_k<<<PREP_BLOCKS, 256, 0, stream>>>(h, W, ss, es, X, Wp);
  fused_k<<<768, 256, 0, stream>>>(X, Wp, span, bias, out);
}

// Round 24
// 49.138 us; speedup vs baseline: 6.6495x; 1.1224x over previous
//
#include <hip/hip_runtime.h>

typedef __attribute__((ext_vector_type(4))) float f32x4;
typedef __attribute__((ext_vector_type(8))) _Float16 f16x8;
typedef __attribute__((ext_vector_type(4))) unsigned short u16x4;

#define NB 8
#define LLEN 512
#define DD 768
#define MW 12
#define HH 384
#define TT (NB * LLEN)      // 4096 tokens
#define SS (LLEN * MW)      // 6144 spans per batch
#define RB 528              // X rows per batch (513 used: t=-1..511, rest pad)
#define MX (NB * RB)        // 4224 X rows

#define BT 64               // tokens per fused block
#define BE 64               // e-slice per block (4 waves x 16 cols)
#define WR2 80              // R-window rows (76 used: t in [T0-1, T0+74])
#define PR2 68              // R-tile LDS pitch in fp16

#define PREPX_BLOCKS ((MX * 192) / 256)   // 3168
#define PREPW_BLOCKS ((DD * 192) / 256)   // 576
#define PREP_BLOCKS (PREPX_BLOCKS + PREPW_BLOCKS)

// ---------- helpers ----------
__device__ __forceinline__ unsigned short f2h(float x) {
  _Float16 h = (_Float16)x;               // RNE
  return __builtin_bit_cast(unsigned short, h);
}
__device__ __forceinline__ float h2f(unsigned short u) {
  return (float)__builtin_bit_cast(_Float16, u);
}
__device__ __forceinline__ void gload_lds16(const void* g, void* l) {
  __builtin_amdgcn_global_load_lds(
      (const __attribute__((address_space(1))) unsigned int*)g,
      (__attribute__((address_space(3))) unsigned int*)l, 16, 0, 0);
}

// ---------- prep (unchanged from R13) ----------
// X[b*RB + t + 1][0:384]   = fwd[b][t]   (ss at t==-1, clamped past 511)
// X[b*RB + t + 1][384:768] = bwd[b][t+1] (es at t>=511)
// Wp[e][k] = fp16(W[e][k])
__global__ __launch_bounds__(256) void prep_k(const float* __restrict__ h,
                                              const float* __restrict__ W,
                                              const float* __restrict__ ss,
                                              const float* __restrict__ es,
                                              unsigned short* __restrict__ X,
                                              unsigned short* __restrict__ Wp) {
  int bid = blockIdx.x;
  if (bid < PREPX_BLOCKS) {
    int idx = bid * 256 + threadIdx.x;        // over MX*192 u16x4 chunks
    int r = idx / 192;
    int c = (idx - r * 192) * 4;
    int b = r / RB;
    int t = r - b * RB - 1;                   // -1..526
    const float* src;
    if (c < HH) {
      src = (t == -1) ? (ss + c) : (h + ((size_t)b * LLEN + min(t, LLEN - 1)) * DD + c);
    } else {
      src = (t >= LLEN - 1) ? (es + (c - HH))
                            : (h + ((size_t)b * LLEN + (t + 1)) * DD + c);
    }
    f32x4 f = *(const f32x4*)src;
    u16x4 v;
#pragma unroll
    for (int j = 0; j < 4; ++j) v[j] = f2h(f[j]);
    *(u16x4*)(X + (size_t)r * DD + c) = v;
  } else {
    int idx = (bid - PREPX_BLOCKS) * 256 + threadIdx.x;  // over DD*192 chunks
    int e = idx / 192;
    int c = (idx - e * 192) * 4;
    f32x4 f = *(const f32x4*)(W + (size_t)e * DD + c);
    u16x4 v;
#pragma unroll
    for (int j = 0; j < 4; ++j) v[j] = f2h(f[j]);
    *(u16x4*)(Wp + (size_t)e * DD + c) = v;
  }
}

// ---------- fused telescoped GEMM + assemble: BT=64 windows ----------
// Per block: batch b, tokens [T0, T0+64), e-slice [E0, E0+64).
// Phase 1: R-window GEMM, M=80 (1.25x halo vs R13's 1.5x -> 17% fewer MFMA),
//          N=64, K=768; proven 2-__syncthreads K-loop (R13 sync structure).
// Phase 2: acc -> fp16 R tile in LDS (union over dead staging).
// Phase 3: out = relu(R[end] - R[start-1] + bias), 2 LDS gathers/row.
// Grid 768 = 12ec x 64win = 3/CU; bid&63 = win -> a window's 12 e-siblings
// share an XCD. T5 setprio around the MFMA cluster (co-resident blocks run
// unsynchronized phases -> scheduler has roles to arbitrate).
__global__ __launch_bounds__(256) void fused_k(const unsigned short* __restrict__ X,
                                               const unsigned short* __restrict__ Wp,
                                               const int* __restrict__ span,
                                               const float* __restrict__ bias,
                                               float* __restrict__ out) {
  __shared__ char lds[WR2 * 128 + BE * 128];   // 18432 B staging / R-tile union
  __shared__ int2 spans[BT * MW];              // 6144 B

  const int bid = blockIdx.x;
  const int g = bid & 63;                  // window id; bid%8 = g%8 (XCD)
  const int ec = bid >> 6;                 // 0..11
  const int b = g >> 3;
  const int T0 = (g & 7) * BT;
  const int E0 = ec * BE;

  const int tid = threadIdx.x;
  const int lane = tid & 63;
  const int wc = tid >> 6;                 // wave -> 16-col slice of N=64
  const int l16 = lane & 15, l4 = lane >> 4;

  // stage this block's 768 spans
  {
    const int2* sp = (const int2*)span + (size_t)b * SS + (size_t)T0 * MW;
    for (int s = tid; s < BT * MW; s += 256) spans[s] = sp[s];
  }

  char* As = lds;                          // [80][128B]  X window slice
  char* Bs = lds + WR2 * 128;              // [64][128B]  Wp slice

  const size_t xbase = (size_t)b * RB + T0;   // X row of window row 0 (t=T0-1)
  const char* Xb = (const char*)X;
  const char* Wb = (const char*)Wp;

  f32x4 acc[5] = {};

  for (int kc = 0; kc < DD; kc += 64) {
    // A: 80 rows x 128 B = 10240 B (2.5 rounds of 256x16B)
#pragma unroll
    for (int r = 0; r < 2; ++r) {
      int o = (r * 256 + tid) * 16;
      int rr = o >> 7, cb = o & 127;
      gload_lds16(Xb + ((xbase + rr) * DD + kc) * 2 + cb, As + o);
    }
    if (tid < 128) {
      int o = 8192 + tid * 16;
      int rr = o >> 7, cb = o & 127;
      gload_lds16(Xb + ((xbase + rr) * DD + kc) * 2 + cb, As + o);
    }
    // B: 64 rows x 128 B = 8192 B (2 rounds)
#pragma unroll
    for (int r = 0; r < 2; ++r) {
      int o = (r * 256 + tid) * 16;
      int rr = o >> 7, cb = o & 127;
      gload_lds16(Wb + ((size_t)(E0 + rr) * DD + kc) * 2 + cb, Bs + o);
    }
    __syncthreads();

    f16x8 af[2][5], bf[2];
#pragma unroll
    for (int ks = 0; ks < 2; ++ks) {
#pragma unroll
      for (int m = 0; m < 5; ++m)
        af[ks][m] = *(const f16x8*)(As + (m * 16 + l16) * 128 + ks * 64 + l4 * 16);
      bf[ks] = *(const f16x8*)(Bs + (wc * 16 + l16) * 128 + ks * 64 + l4 * 16);
    }
    __builtin_amdgcn_s_setprio(1);
#pragma unroll
    for (int m = 0; m < 5; ++m) {
      acc[m] = __builtin_amdgcn_mfma_f32_16x16x32_f16(af[0][m], bf[0], acc[m], 0, 0, 0);
      acc[m] = __builtin_amdgcn_mfma_f32_16x16x32_f16(af[1][m], bf[1], acc[m], 0, 0, 0);
    }
    __builtin_amdgcn_s_setprio(0);
    __syncthreads();                       // staging reusable / dead after last iter
  }

  // Phase 2: acc -> fp16 R tile (unions over dead staging)
  unsigned short* Rt = (unsigned short*)lds;   // [80][PR2]; row rr = R[T0-1+rr]
#pragma unroll
  for (int m = 0; m < 5; ++m) {
    int row = m * 16 + l4 * 4;
    int col = wc * 16 + l16;
#pragma unroll
    for (int r = 0; r < 4; ++r)
      Rt[(row + r) * PR2 + col] = f2h(acc[m][r]);
  }
  __syncthreads();

  // Phase 3: out[b, (T0+l)*12+w, E0:E0+64] = relu(R[end] - R[start-1] + b)
  const u16x4* R4 = (const u16x4*)Rt;      // row pitch PR2/4 = 17
  const f32x4* bias4 = (const f32x4*)bias;
  f32x4* out4 = (f32x4*)out + ((size_t)b * SS + (size_t)T0 * MW) * (DD / 4) + (E0 >> 2);

  const int e4 = tid & 15;                 // 16 u16x4 chunks per 64-e slice
  int lw = tid >> 4;                       // token-width row, +16 per iter
  const f32x4 bb = bias4[(E0 >> 2) + e4];
#pragma unroll 4
  for (int it = 0; it < (BT * MW) / 16; ++it) {   // 48 iters
    const int2 se = spans[lw];
    u16x4 pe = R4[(se.y - T0 + 1) * 17 + e4];     // R[end]
    u16x4 mq = R4[(se.x - T0) * 17 + e4];         // R[start-1]
    f32x4 r;
#pragma unroll
    for (int j = 0; j < 4; ++j) {
      float x = h2f(pe[j]) - h2f(mq[j]) + bb[j];
      r[j] = fmaxf(x, 0.f);
    }
    out4[(size_t)lw * (DD / 4) + e4] = r;
    lw += 16;
  }
}

// ---------- naive fallback (only if ws too small) ----------
__global__ __launch_bounds__(256) void naive_k(const float* __restrict__ h,
                                               const int* __restrict__ span,
                                               const float* __restrict__ W,
                                               const float* __restrict__ bias,
                                               const float* __restrict__ ss,
                                               const float* __restrict__ es,
                                               float* __restrict__ out) {
  int bs = blockIdx.x;
  int b = bs / SS;
  int start = span[(size_t)bs * 2 + 0];
  int end   = span[(size_t)bs * 2 + 1];
  __shared__ float rep[DD];
  const float* hb = h + (size_t)b * LLEN * DD;
  for (int k = threadIdx.x; k < HH; k += blockDim.x) {
    float fs = (start == 0) ? ss[k] : hb[(size_t)(start - 1) * DD + k];
    rep[k] = hb[(size_t)end * DD + k] - fs;
    float bstart = (end + 1 >= LLEN) ? es[k] : hb[(size_t)(end + 1) * DD + HH + k];
    rep[HH + k] = bstart - hb[(size_t)start * DD + HH + k];
  }
  __syncthreads();
  for (int e = threadIdx.x; e < DD; e += blockDim.x) {
    const float* w = W + (size_t)e * DD;
    float acc = bias[e];
    for (int k = 0; k < DD; k += 4) {
      acc += rep[k] * w[k] + rep[k + 1] * w[k + 1] + rep[k + 2] * w[k + 2] + rep[k + 3] * w[k + 3];
    }
    out[(size_t)bs * DD + e] = fmaxf(acc, 0.f);
  }
}

extern "C" void kernel_launch(void* const* d_in, const int* in_sizes, int n_in,
                              void* d_out, int out_size, void* d_ws, size_t ws_size,
                              hipStream_t stream) {
  const float* h  = (const float*)d_in[0];
  const int* span = (const int*)d_in[1];
  const float* W  = (const float*)d_in[2];
  const float* bias = (const float*)d_in[3];
  const float* ss = (const float*)d_in[4];
  const float* es = (const float*)d_in[5];
  float* out = (float*)d_out;

  const size_t szX = (size_t)MX * DD * sizeof(unsigned short);    // 6.49 MB
  const size_t szW = (size_t)DD * DD * sizeof(unsigned short);    // 1.18 MB
  const size_t need = szX + szW;                                  // ~7.7 MB

  if (ws_size < need) {
    naive_k<<<NB * SS, 256, 0, stream>>>(h, span, W, bias, ss, es, out);
    return;
  }

  char* ws = (char*)d_ws;
  unsigned short* X  = (unsigned short*)ws;                // [MX][DD] fp16
  unsigned short* Wp = X + (size_t)MX * DD;                // [DD][DD] fp16

  prep_k<<<PREP_BLOCKS, 256, 0, stream>>>(h, W, ss, es, X, Wp);
  fused_k<<<768, 256, 0, stream>>>(X, Wp, span, bias, out);
}